// Round 1
// baseline (297.937 us; speedup 1.0000x reference)
//
#include <hip/hip_runtime.h>

// ---------------------------------------------------------------------------
// Problem geometry (compile-time):
//   B=16, H=W=1024, ROUTE kh0=512 kw0=256  -> ph=2, pw=4, L=8 patches/image
//   scale i: kh=512>>i, kw=256>>i, image dim = 1024>>i
//   128 (b,l) patches total; 4 scales.
// Chunk size for the error pass: 2048 px per block (256 thr x 2 float4).
//   chunks/patch: s0=64, s1=16, s2=4, s3=1 -> block offsets {0,8192,10240,10752}
//   total blocks = 10880
// ---------------------------------------------------------------------------

__global__ __launch_bounds__(256) void k_err(
    const float* __restrict__ pre0, const float* __restrict__ gt0,
    const float* __restrict__ pre1, const float* __restrict__ gt1,
    const float* __restrict__ pre2, const float* __restrict__ gt2,
    const float* __restrict__ pre3, const float* __restrict__ gt3,
    float* __restrict__ partials)
{
    const int bid = blockIdx.x;
    int scale, patch, chunk;
    const float* __restrict__ pre;
    const float* __restrict__ gt;
    if (bid < 8192)       { scale = 0; patch = bid >> 6;            chunk = bid & 63;            pre = pre0; gt = gt0; }
    else if (bid < 10240) { scale = 1; int r = bid - 8192;  patch = r >> 4; chunk = r & 15; pre = pre1; gt = gt1; }
    else if (bid < 10752) { scale = 2; int r = bid - 10240; patch = r >> 2; chunk = r & 3;  pre = pre2; gt = gt2; }
    else                  { scale = 3; int r = bid - 10752; patch = r;      chunk = 0;      pre = pre3; gt = gt3; }

    const int b  = patch >> 3;
    const int l  = patch & 7;
    const int pi = l >> 2, pj = l & 3;
    const int kwshift = 8 - scale;            // kw = 256>>scale
    const int kw   = 1 << kwshift;
    const int kh   = 512 >> scale;
    const int wdim = 1024 >> scale;
    const size_t imgbase  = (size_t)b * (size_t)wdim * (size_t)wdim;
    const int    base_row = pi * kh;
    const int    base_col = pj * kw;

    const int t = threadIdx.x;
    float sumabs = 0.f, npos = 0.f, sq = 0.f;

#pragma unroll
    for (int s = 0; s < 2; ++s) {
        const int slot = t + s * 256;                 // 0..511 float4 slots
        const int px   = chunk * 2048 + slot * 4;     // pixel index within patch
        const int row  = px >> kwshift;
        const int col  = px & (kw - 1);
        const size_t idx = imgbase + (size_t)(base_row + row) * wdim + base_col + col;
        const float4 p = *reinterpret_cast<const float4*>(pre + idx);
        const float4 g = *reinterpret_cast<const float4*>(gt + idx);
        const float pv[4] = {p.x, p.y, p.z, p.w};
        const float gv[4] = {g.x, g.y, g.z, g.w};
#pragma unroll
        for (int k = 0; k < 4; ++k) {
            const float gs = gv[k] * 200.0f;          // gts = gt * WEIGHT
            const float d  = gs - pv[k];
            sq += d * d;                              // loss term: all pixels
            if (gv[k] > 0.0f) { sumabs += fabsf(d); npos += 1.0f; }
        }
    }

    __shared__ float sA[256], sN[256], sQ[256];
    sA[t] = sumabs; sN[t] = npos; sQ[t] = sq;
    __syncthreads();
    for (int off = 128; off > 0; off >>= 1) {
        if (t < off) { sA[t] += sA[t + off]; sN[t] += sN[t + off]; sQ[t] += sQ[t + off]; }
        __syncthreads();
    }
    if (t == 0) {
        partials[3 * bid + 0] = sA[0];
        partials[3 * bid + 1] = sN[0];
        partials[3 * bid + 2] = sQ[0];
    }
}

// One wave per (b,l) patch: reduce the per-chunk partials for each scale,
// compute e_i = sumabs/(npos+0.1), pick argmin (first-min tie-break),
// record selected scale and its sum-of-squares.
__global__ __launch_bounds__(64) void k_argmin(
    const float* __restrict__ partials, int* __restrict__ mask, float* __restrict__ sqsel)
{
    const int patch = blockIdx.x;     // 0..127
    const int t = threadIdx.x;        // 0..63 (one wave)
    const int bases[4] = {0, 8192, 10240, 10752};
    const int nch[4]   = {64, 16, 4, 1};
    float e[4], q[4];
#pragma unroll
    for (int i = 0; i < 4; ++i) {
        float a = 0.f, c = 0.f, s = 0.f;
        if (t < nch[i]) {
            const int idx = bases[i] + patch * nch[i] + t;
            a = partials[3 * idx + 0];
            c = partials[3 * idx + 1];
            s = partials[3 * idx + 2];
        }
        for (int off = 32; off > 0; off >>= 1) {
            a += __shfl_down(a, off);
            c += __shfl_down(c, off);
            s += __shfl_down(s, off);
        }
        e[i] = a / (c + 0.1f);
        q[i] = s;
    }
    if (t == 0) {
        int best = 0; float bv = e[0];
#pragma unroll
        for (int i = 1; i < 4; ++i) if (e[i] < bv) { bv = e[i]; best = i; }
        const float qb = (best == 0) ? q[0] : (best == 1) ? q[1] : (best == 2) ? q[2] : q[3];
        mask[patch]  = best;
        sqsel[patch] = qb;
    }
}

// Single block: deterministic loss reduction over the 128 patches.
__global__ __launch_bounds__(128) void k_loss(
    const int* __restrict__ mask, const float* __restrict__ sqsel, float* __restrict__ loss_out)
{
    const int t = threadIdx.x;        // 0..127
    const int   m = mask[t];
    const float q = sqsel[t];
    __shared__ float sQ[128], sC[128];
    float loss = 0.f;
    const float w[4] = {0.5f, 0.25f, 0.125f, 0.0625f};
#pragma unroll
    for (int i = 0; i < 4; ++i) {
        sQ[t] = (m == i) ? q   : 0.f;
        sC[t] = (m == i) ? 1.f : 0.f;
        __syncthreads();
        for (int off = 64; off > 0; off >>= 1) {
            if (t < off) { sQ[t] += sQ[t + off]; sC[t] += sC[t + off]; }
            __syncthreads();
        }
        if (t == 0) {
            const float px = (float)(131072 >> (2 * i));   // kh_i * kw_i
            loss += w[i] * (sQ[0] / (sC[0] * px + 0.01f));
        }
        __syncthreads();
    }
    if (t == 0) loss_out[0] = loss;
}

// Output pass: one thread per output pixel (scalar, coalesced — out_img
// starts at d_out+1 so float4 stores would be misaligned).
__global__ __launch_bounds__(256) void k_write(
    const float* __restrict__ pre0, const float* __restrict__ gt0,
    const float* __restrict__ pre1, const float* __restrict__ gt1,
    const float* __restrict__ pre2, const float* __restrict__ gt2,
    const float* __restrict__ pre3, const float* __restrict__ gt3,
    const int* __restrict__ mask,
    float* __restrict__ out_img, float* __restrict__ lab_img)
{
    const int tid = blockIdx.x * 256 + threadIdx.x;   // < 16,777,216
    const int b = tid >> 20;
    const int y = (tid >> 10) & 1023;
    const int x = tid & 1023;
    const int pi = y >> 9, pj = x >> 8;
    const int r  = y & 511, c = x & 255;
    const int m  = mask[(b << 3) + (pi << 2) + pj];    // wave-uniform
    const int kh = 512 >> m, kw = 256 >> m;
    const int pad_h = (512 - kh) >> 1;
    const int pad_w = (256 - kw) >> 1;
    const unsigned rr = (unsigned)(r - pad_h);
    const unsigned cc = (unsigned)(c - pad_w);
    float ov, lv;
    if (rr < (unsigned)kh && cc < (unsigned)kw) {
        const int wdim = 1024 >> m;
        const float* __restrict__ pre = (m == 0) ? pre0 : (m == 1) ? pre1 : (m == 2) ? pre2 : pre3;
        const float* __restrict__ gt  = (m == 0) ? gt0  : (m == 1) ? gt1  : (m == 2) ? gt2  : gt3;
        const size_t idx = (size_t)b * wdim * wdim
                         + (size_t)(pi * kh + (int)rr) * wdim
                         + (size_t)(pj * kw + (int)cc);
        ov = pre[idx] * (1.0f / 200.0f);   // outputs / WEIGHT
        lv = gt[idx];                      // (gt*WEIGHT)/WEIGHT
    } else {
        ov = 0.2f / 200.0f;                // pad constant / WEIGHT
        lv = 0.2f / 200.0f;
    }
    out_img[tid] = ov;
    lab_img[tid] = lv;
}

extern "C" void kernel_launch(void* const* d_in, const int* in_sizes, int n_in,
                              void* d_out, int out_size, void* d_ws, size_t ws_size,
                              hipStream_t stream) {
    // setup_inputs() dict order is INTERLEAVED: pre0, gt0, pre1, gt1, ...
    const float* pre0 = (const float*)d_in[0];
    const float* gt0  = (const float*)d_in[1];
    const float* pre1 = (const float*)d_in[2];
    const float* gt1  = (const float*)d_in[3];
    const float* pre2 = (const float*)d_in[4];
    const float* gt2  = (const float*)d_in[5];
    const float* pre3 = (const float*)d_in[6];
    const float* gt3  = (const float*)d_in[7];

    float* out = (float*)d_out;                       // [0]=loss, [1..]=out_img, then lab_img
    float* partials = (float*)d_ws;                   // 10880*3 floats
    int*   mask     = (int*)((float*)d_ws + 32640);   // 128 ints
    float* sqsel    = (float*)d_ws + 32640 + 128;     // 128 floats

    k_err<<<10880, 256, 0, stream>>>(pre0, gt0, pre1, gt1, pre2, gt2, pre3, gt3, partials);
    k_argmin<<<128, 64, 0, stream>>>(partials, mask, sqsel);
    k_loss<<<1, 128, 0, stream>>>(mask, sqsel, out);

    const int NPIX = 16 * 1024 * 1024;                // B*H*W
    k_write<<<NPIX / 256, 256, 0, stream>>>(pre0, gt0, pre1, gt1, pre2, gt2, pre3, gt3,
                                            mask, out + 1, out + 1 + NPIX);
}

// Round 3
// 292.439 us; speedup vs baseline: 1.0188x; 1.0188x over previous
//
#include <hip/hip_runtime.h>

// ---------------------------------------------------------------------------
// Geometry (compile-time): B=16, H=W=1024, kh0=512 kw0=256 -> ph=2, pw=4, L=8
// 128 (b,l) patches; 4 scales (kh,kw,dim halve per scale).
// Pass 1 (k_err): per 2048-px chunk partial sums. Block offsets:
//   s0: 8192 blocks, s1: 2048, s2: 512, s3: 128 -> 10880 total.
// Partials stored SoA, chunk-major within scale: id = base_i + chunk*128 + patch
//   bases {0, 8192, 10240, 10752}, total 10880 per plane (A,N,Q planes).
// Pass 2 (k_finalize): 1 block, coalesced reduce -> argmin mask + loss.
// Pass 3 (k_write): 4 px/thread, 16B-aligned float4 nontemporal stores
//   (d_out+1 base => groups starting at i == 3 mod 4 are aligned).
// ---------------------------------------------------------------------------

typedef float f32x4 __attribute__((ext_vector_type(4)));

__global__ __launch_bounds__(256) void k_err(
    const float* __restrict__ pre0, const float* __restrict__ gt0,
    const float* __restrict__ pre1, const float* __restrict__ gt1,
    const float* __restrict__ pre2, const float* __restrict__ gt2,
    const float* __restrict__ pre3, const float* __restrict__ gt3,
    float* __restrict__ pA, float* __restrict__ pN, float* __restrict__ pQ)
{
    const int bid = blockIdx.x;
    int scale, patch, chunk, oidx;
    const float* __restrict__ pre;
    const float* __restrict__ gt;
    if (bid < 8192)       { scale = 0; patch = bid >> 6; chunk = bid & 63;
                            oidx = chunk * 128 + patch;          pre = pre0; gt = gt0; }
    else if (bid < 10240) { scale = 1; int r = bid - 8192;  patch = r >> 4; chunk = r & 15;
                            oidx = 8192 + chunk * 128 + patch;   pre = pre1; gt = gt1; }
    else if (bid < 10752) { scale = 2; int r = bid - 10240; patch = r >> 2; chunk = r & 3;
                            oidx = 10240 + chunk * 128 + patch;  pre = pre2; gt = gt2; }
    else                  { scale = 3; patch = bid - 10752; chunk = 0;
                            oidx = 10752 + patch;                pre = pre3; gt = gt3; }

    const int b  = patch >> 3;
    const int l  = patch & 7;
    const int pi = l >> 2, pj = l & 3;
    const int kwshift = 8 - scale;            // kw = 256>>scale
    const int kw   = 1 << kwshift;
    const int kh   = 512 >> scale;
    const int wdim = 1024 >> scale;
    const int imgbase  = b * wdim * wdim;     // < 2^24, int is fine
    const int base_row = pi * kh;
    const int base_col = pj * kw;

    const int t = threadIdx.x;
    float sumabs = 0.f, npos = 0.f, sq = 0.f;

#pragma unroll
    for (int s = 0; s < 2; ++s) {
        const int slot = t + s * 256;                 // 0..511 float4 slots
        const int px   = chunk * 2048 + slot * 4;     // pixel index within patch
        const int row  = px >> kwshift;
        const int col  = px & (kw - 1);
        const int idx  = imgbase + (base_row + row) * wdim + base_col + col;
        const f32x4 p = *reinterpret_cast<const f32x4*>(pre + idx);
        const f32x4 g = *reinterpret_cast<const f32x4*>(gt + idx);
#pragma unroll
        for (int k = 0; k < 4; ++k) {
            const float gs = g[k] * 200.0f;           // gts = gt * WEIGHT
            const float d  = gs - p[k];
            sq += d * d;                              // loss term: all pixels
            if (g[k] > 0.0f) { sumabs += fabsf(d); npos += 1.0f; }
        }
    }

    // wave shuffle reduce (fixed order -> deterministic), then 4-wave combine
    for (int off = 32; off > 0; off >>= 1) {
        sumabs += __shfl_down(sumabs, off);
        npos   += __shfl_down(npos,   off);
        sq     += __shfl_down(sq,     off);
    }
    __shared__ float wA[4], wN[4], wQ[4];
    const int w = t >> 6;
    if ((t & 63) == 0) { wA[w] = sumabs; wN[w] = npos; wQ[w] = sq; }
    __syncthreads();
    if (t == 0) {
        pA[oidx] = (wA[0] + wA[1]) + (wA[2] + wA[3]);
        pN[oidx] = (wN[0] + wN[1]) + (wN[2] + wN[3]);
        pQ[oidx] = (wQ[0] + wQ[1]) + (wQ[2] + wQ[3]);
    }
}

// One block, 256 threads: reduce partials per (scale,patch) with coalesced
// chunk-major reads, compute e_i, argmin (first-min tie-break), mask, loss.
__global__ __launch_bounds__(256) void k_finalize(
    const float* __restrict__ pA, const float* __restrict__ pN, const float* __restrict__ pQ,
    int* __restrict__ mask, float* __restrict__ loss_out)
{
    const int t = threadIdx.x;
    __shared__ float A[512], N[512], Q[512];   // [i*128 + p]
    __shared__ float qsel[128];
    __shared__ int   msel[128];

    // thread t<128: tasks (i=0,p=t),(i=2,p=t); t>=128: (i=1,p),(i=3,p)
    const int p  = t & 127;
    const int i0 = (t < 128) ? 0 : 1;
#pragma unroll
    for (int k = 0; k < 2; ++k) {
        const int i    = i0 + 2 * k;
        const int base = (i == 0) ? 0 : (i == 1) ? 8192 : (i == 2) ? 10240 : 10752;
        const int nch  = 64 >> (2 * i);
        float a = 0.f, n = 0.f, q = 0.f;
#pragma unroll 4
        for (int c = 0; c < nch; ++c) {
            const int id = base + c * 128 + p;     // lanes p consecutive: coalesced
            a += pA[id]; n += pN[id]; q += pQ[id];
        }
        A[i * 128 + p] = a; N[i * 128 + p] = n; Q[i * 128 + p] = q;
    }
    __syncthreads();

    if (t < 128) {
        const float e0 = A[t]       / (N[t]       + 0.1f);
        const float e1 = A[128 + t] / (N[128 + t] + 0.1f);
        const float e2 = A[256 + t] / (N[256 + t] + 0.1f);
        const float e3 = A[384 + t] / (N[384 + t] + 0.1f);
        int best = 0; float bv = e0;
        if (e1 < bv) { bv = e1; best = 1; }
        if (e2 < bv) { bv = e2; best = 2; }
        if (e3 < bv) { bv = e3; best = 3; }
        mask[t] = best;
        msel[t] = best;
        qsel[t] = Q[best * 128 + t];
    }
    __syncthreads();

    float loss = 0.f;
    const float wgt[4] = {0.5f, 0.25f, 0.125f, 0.0625f};
#pragma unroll
    for (int i = 0; i < 4; ++i) {
        if (t < 128) { A[t] = (msel[t] == i) ? qsel[t] : 0.f;
                       N[t] = (msel[t] == i) ? 1.f     : 0.f; }
        __syncthreads();
        for (int off = 64; off > 0; off >>= 1) {
            if (t < off) { A[t] += A[t + off]; N[t] += N[t + off]; }
            __syncthreads();
        }
        if (t == 0) {
            const float px = (float)(131072 >> (2 * i));   // kh_i*kw_i
            loss += wgt[i] * (A[0] / (N[0] * px + 0.01f));
        }
        __syncthreads();
    }
    if (t == 0) loss_out[0] = loss;
}

__device__ __forceinline__ void px_val(
    int i,
    const float* __restrict__ pre0, const float* __restrict__ gt0,
    const float* __restrict__ pre1, const float* __restrict__ gt1,
    const float* __restrict__ pre2, const float* __restrict__ gt2,
    const float* __restrict__ pre3, const float* __restrict__ gt3,
    const int* __restrict__ mask, float& ov, float& lv)
{
    const int b = i >> 20;
    const int y = (i >> 10) & 1023;
    const int x = i & 1023;
    const int pi = y >> 9, pj = x >> 8;
    const int r  = y & 511, c = x & 255;
    const int m  = mask[(b << 3) + (pi << 2) + pj];
    const int kh = 512 >> m, kw = 256 >> m;
    const unsigned rr = (unsigned)(r - ((512 - kh) >> 1));
    const unsigned cc = (unsigned)(c - ((256 - kw) >> 1));
    if (rr < (unsigned)kh && cc < (unsigned)kw) {
        const int wdim = 1024 >> m;
        const float* __restrict__ pre = (m == 0) ? pre0 : (m == 1) ? pre1 : (m == 2) ? pre2 : pre3;
        const float* __restrict__ gt  = (m == 0) ? gt0  : (m == 1) ? gt1  : (m == 2) ? gt2  : gt3;
        const int idx = b * wdim * wdim + (pi * kh + (int)rr) * wdim + (pj * kw + (int)cc);
        ov = pre[idx] * (1.0f / 200.0f);
        lv = gt[idx];
    } else {
        ov = 0.001f;       // 0.2 / WEIGHT
        lv = 0.001f;
    }
}

// 4 px/thread; stores are 16B-aligned float4 (groups start at i==3 mod 4
// because out_img lives at d_out+1). Last thread mops up pixels {0,1,2,last}.
__global__ __launch_bounds__(256) void k_write(
    const float* __restrict__ pre0, const float* __restrict__ gt0,
    const float* __restrict__ pre1, const float* __restrict__ gt1,
    const float* __restrict__ pre2, const float* __restrict__ gt2,
    const float* __restrict__ pre3, const float* __restrict__ gt3,
    const int* __restrict__ mask, float* __restrict__ out)
{
    const int NPIX = 16 * 1024 * 1024;
    const int j = blockIdx.x * 256 + threadIdx.x;    // < 4,194,304
    float* __restrict__ out_img = out + 1;
    float* __restrict__ lab_img = out + 1 + NPIX;

    if (j < 4194303) {
        const int i0 = 4 * j + 3;
        f32x4 o4, l4;
#pragma unroll
        for (int p = 0; p < 4; ++p) {
            float ov, lv;
            px_val(i0 + p, pre0, gt0, pre1, gt1, pre2, gt2, pre3, gt3, mask, ov, lv);
            o4[p] = ov; l4[p] = lv;
        }
        __builtin_nontemporal_store(o4, reinterpret_cast<f32x4*>(out_img + i0));
        __builtin_nontemporal_store(l4, reinterpret_cast<f32x4*>(lab_img + i0));
    } else {
        const int edge[4] = {0, 1, 2, NPIX - 1};
#pragma unroll
        for (int p = 0; p < 4; ++p) {
            float ov, lv;
            px_val(edge[p], pre0, gt0, pre1, gt1, pre2, gt2, pre3, gt3, mask, ov, lv);
            out_img[edge[p]] = ov;
            lab_img[edge[p]] = lv;
        }
    }
}

extern "C" void kernel_launch(void* const* d_in, const int* in_sizes, int n_in,
                              void* d_out, int out_size, void* d_ws, size_t ws_size,
                              hipStream_t stream) {
    // setup_inputs() dict order is INTERLEAVED: pre0, gt0, pre1, gt1, ...
    const float* pre0 = (const float*)d_in[0];
    const float* gt0  = (const float*)d_in[1];
    const float* pre1 = (const float*)d_in[2];
    const float* gt1  = (const float*)d_in[3];
    const float* pre2 = (const float*)d_in[4];
    const float* gt2  = (const float*)d_in[5];
    const float* pre3 = (const float*)d_in[6];
    const float* gt3  = (const float*)d_in[7];

    float* out = (float*)d_out;             // [0]=loss, [1..]=out_img, then lab_img
    float* pA  = (float*)d_ws;              // 10880 each, SoA planes
    float* pN  = pA + 10880;
    float* pQ  = pA + 21760;
    int*   mask = (int*)(pA + 32640);       // 128 ints

    k_err<<<10880, 256, 0, stream>>>(pre0, gt0, pre1, gt1, pre2, gt2, pre3, gt3, pA, pN, pQ);
    k_finalize<<<1, 256, 0, stream>>>(pA, pN, pQ, mask, out);
    k_write<<<16384, 256, 0, stream>>>(pre0, gt0, pre1, gt1, pre2, gt2, pre3, gt3, mask, out);
}

// Round 5
// 289.918 us; speedup vs baseline: 1.0277x; 1.0087x over previous
//
#include <hip/hip_runtime.h>

// ---------------------------------------------------------------------------
// Geometry (compile-time): B=16, H=W=1024, kh0=512 kw0=256 -> ph=2, pw=4, L=8
// 128 (b,l) patches; 4 scales (kh,kw,dim halve per scale).
// Pass 1 (k_err): 4096-px chunks, 4 f32x4-slot iterations per thread.
//   blocks/patch: s0=32, s1=8, s2=2, s3=1 -> bases {0,4096,5120,5376}, 5504 total
//   (scale 3 patch is 2048 px: the px<patch_px predicate trims its chunk)
//   Partials SoA chunk-major: id = base_i + chunk*128 + patch (planes A,N,Q).
// Pass 2 (k_finalize): 1 block, coalesced reduce -> argmin mask + loss.
//   chunks/patch table is EXPLICIT {32,8,2,1} (round-4 bug: 32>>(2*3)==0).
// Pass 3 (k_write): 4 px/thread, 16B-aligned float4 nontemporal stores
//   (d_out+1 base => groups starting at i == 3 mod 4 are aligned).
// ---------------------------------------------------------------------------

typedef float f32x4 __attribute__((ext_vector_type(4)));

__global__ __launch_bounds__(256) void k_err(
    const float* __restrict__ pre0, const float* __restrict__ gt0,
    const float* __restrict__ pre1, const float* __restrict__ gt1,
    const float* __restrict__ pre2, const float* __restrict__ gt2,
    const float* __restrict__ pre3, const float* __restrict__ gt3,
    float* __restrict__ pA, float* __restrict__ pN, float* __restrict__ pQ)
{
    const int bid = blockIdx.x;
    int scale, patch, chunk, oidx;
    const float* __restrict__ pre;
    const float* __restrict__ gt;
    if (bid < 4096)      { scale = 0; patch = bid >> 5; chunk = bid & 31;
                           oidx = chunk * 128 + patch;          pre = pre0; gt = gt0; }
    else if (bid < 5120) { scale = 1; int r = bid - 4096; patch = r >> 3; chunk = r & 7;
                           oidx = 4096 + chunk * 128 + patch;   pre = pre1; gt = gt1; }
    else if (bid < 5376) { scale = 2; int r = bid - 5120; patch = r >> 1; chunk = r & 1;
                           oidx = 5120 + chunk * 128 + patch;   pre = pre2; gt = gt2; }
    else                 { scale = 3; patch = bid - 5376; chunk = 0;
                           oidx = 5376 + patch;                 pre = pre3; gt = gt3; }

    const int b  = patch >> 3;
    const int l  = patch & 7;
    const int pi = l >> 2, pj = l & 3;
    const int kwshift = 8 - scale;            // kw = 256>>scale
    const int kw   = 1 << kwshift;
    const int kh   = 512 >> scale;
    const int wdim = 1024 >> scale;
    const int patch_px = 131072 >> (2 * scale);
    const int imgbase  = b * wdim * wdim;     // < 2^24, int is fine
    const int base_row = pi * kh;
    const int base_col = pj * kw;

    const int t = threadIdx.x;
    float sumabs = 0.f, npos = 0.f, sq = 0.f;

#pragma unroll
    for (int s = 0; s < 4; ++s) {
        const int slot = t + s * 256;                 // 0..1023 float4 slots
        const int px   = chunk * 4096 + slot * 4;     // pixel index within patch
        if (px < patch_px) {                          // wave-uniform (only s3 trims)
            const int row  = px >> kwshift;
            const int col  = px & (kw - 1);
            const int idx  = imgbase + (base_row + row) * wdim + base_col + col;
            const f32x4 p = *reinterpret_cast<const f32x4*>(pre + idx);
            const f32x4 g = *reinterpret_cast<const f32x4*>(gt + idx);
#pragma unroll
            for (int k = 0; k < 4; ++k) {
                const float gs = g[k] * 200.0f;       // gts = gt * WEIGHT
                const float d  = gs - p[k];
                sq += d * d;                          // loss term: all pixels
                if (g[k] > 0.0f) { sumabs += fabsf(d); npos += 1.0f; }
            }
        }
    }

    // wave shuffle reduce (fixed order -> deterministic), then 4-wave combine
    for (int off = 32; off > 0; off >>= 1) {
        sumabs += __shfl_down(sumabs, off);
        npos   += __shfl_down(npos,   off);
        sq     += __shfl_down(sq,     off);
    }
    __shared__ float wA[4], wN[4], wQ[4];
    const int w = t >> 6;
    if ((t & 63) == 0) { wA[w] = sumabs; wN[w] = npos; wQ[w] = sq; }
    __syncthreads();
    if (t == 0) {
        pA[oidx] = (wA[0] + wA[1]) + (wA[2] + wA[3]);
        pN[oidx] = (wN[0] + wN[1]) + (wN[2] + wN[3]);
        pQ[oidx] = (wQ[0] + wQ[1]) + (wQ[2] + wQ[3]);
    }
}

// One block, 256 threads: reduce partials per (scale,patch) with coalesced
// chunk-major reads, compute e_i, argmin (first-min tie-break), mask, loss.
__global__ __launch_bounds__(256) void k_finalize(
    const float* __restrict__ pA, const float* __restrict__ pN, const float* __restrict__ pQ,
    int* __restrict__ mask, float* __restrict__ loss_out)
{
    const int t = threadIdx.x;
    __shared__ float A[512], N[512], Q[512];   // [i*128 + p]
    __shared__ float qsel[128];
    __shared__ int   msel[128];

    // thread t<128: tasks (i=0,p=t),(i=2,p=t); t>=128: (i=1,p),(i=3,p)
    const int p  = t & 127;
    const int i0 = (t < 128) ? 0 : 1;
#pragma unroll
    for (int k = 0; k < 2; ++k) {
        const int i    = i0 + 2 * k;
        const int base = (i == 0) ? 0 : (i == 1) ? 4096 : (i == 2) ? 5120 : 5376;
        const int nch  = (i == 0) ? 32 : (i == 1) ? 8 : (i == 2) ? 2 : 1;   // EXPLICIT
        float a = 0.f, n = 0.f, q = 0.f;
#pragma unroll 4
        for (int c = 0; c < nch; ++c) {
            const int id = base + c * 128 + p;     // lanes p consecutive: coalesced
            a += pA[id]; n += pN[id]; q += pQ[id];
        }
        A[i * 128 + p] = a; N[i * 128 + p] = n; Q[i * 128 + p] = q;
    }
    __syncthreads();

    if (t < 128) {
        const float e0 = A[t]       / (N[t]       + 0.1f);
        const float e1 = A[128 + t] / (N[128 + t] + 0.1f);
        const float e2 = A[256 + t] / (N[256 + t] + 0.1f);
        const float e3 = A[384 + t] / (N[384 + t] + 0.1f);
        int best = 0; float bv = e0;
        if (e1 < bv) { bv = e1; best = 1; }
        if (e2 < bv) { bv = e2; best = 2; }
        if (e3 < bv) { bv = e3; best = 3; }
        mask[t] = best;
        msel[t] = best;
        qsel[t] = Q[best * 128 + t];
    }
    __syncthreads();

    float loss = 0.f;
    const float wgt[4] = {0.5f, 0.25f, 0.125f, 0.0625f};
#pragma unroll
    for (int i = 0; i < 4; ++i) {
        if (t < 128) { A[t] = (msel[t] == i) ? qsel[t] : 0.f;
                       N[t] = (msel[t] == i) ? 1.f     : 0.f; }
        __syncthreads();
        for (int off = 64; off > 0; off >>= 1) {
            if (t < off) { A[t] += A[t + off]; N[t] += N[t + off]; }
            __syncthreads();
        }
        if (t == 0) {
            const float px = (float)(131072 >> (2 * i));   // kh_i*kw_i
            loss += wgt[i] * (A[0] / (N[0] * px + 0.01f));
        }
        __syncthreads();
    }
    if (t == 0) loss_out[0] = loss;
}

__device__ __forceinline__ void px_val(
    int i,
    const float* __restrict__ pre0, const float* __restrict__ gt0,
    const float* __restrict__ pre1, const float* __restrict__ gt1,
    const float* __restrict__ pre2, const float* __restrict__ gt2,
    const float* __restrict__ pre3, const float* __restrict__ gt3,
    const int* __restrict__ mask, float& ov, float& lv)
{
    const int b = i >> 20;
    const int y = (i >> 10) & 1023;
    const int x = i & 1023;
    const int pi = y >> 9, pj = x >> 8;
    const int r  = y & 511, c = x & 255;
    const int m  = mask[(b << 3) + (pi << 2) + pj];
    const int kh = 512 >> m, kw = 256 >> m;
    const unsigned rr = (unsigned)(r - ((512 - kh) >> 1));
    const unsigned cc = (unsigned)(c - ((256 - kw) >> 1));
    if (rr < (unsigned)kh && cc < (unsigned)kw) {
        const int wdim = 1024 >> m;
        const float* __restrict__ pre = (m == 0) ? pre0 : (m == 1) ? pre1 : (m == 2) ? pre2 : pre3;
        const float* __restrict__ gt  = (m == 0) ? gt0  : (m == 1) ? gt1  : (m == 2) ? gt2  : gt3;
        const int idx = b * wdim * wdim + (pi * kh + (int)rr) * wdim + (pj * kw + (int)cc);
        ov = pre[idx] * (1.0f / 200.0f);
        lv = gt[idx];
    } else {
        ov = 0.001f;       // 0.2 / WEIGHT
        lv = 0.001f;
    }
}

// 4 px/thread; stores are 16B-aligned float4 (groups start at i==3 mod 4
// because out_img lives at d_out+1). Last thread mops up pixels {0,1,2,last}.
__global__ __launch_bounds__(256) void k_write(
    const float* __restrict__ pre0, const float* __restrict__ gt0,
    const float* __restrict__ pre1, const float* __restrict__ gt1,
    const float* __restrict__ pre2, const float* __restrict__ gt2,
    const float* __restrict__ pre3, const float* __restrict__ gt3,
    const int* __restrict__ mask, float* __restrict__ out)
{
    const int NPIX = 16 * 1024 * 1024;
    const int j = blockIdx.x * 256 + threadIdx.x;    // < 4,194,304
    float* __restrict__ out_img = out + 1;
    float* __restrict__ lab_img = out + 1 + NPIX;

    if (j < 4194303) {
        const int i0 = 4 * j + 3;
        f32x4 o4, l4;
#pragma unroll
        for (int p = 0; p < 4; ++p) {
            float ov, lv;
            px_val(i0 + p, pre0, gt0, pre1, gt1, pre2, gt2, pre3, gt3, mask, ov, lv);
            o4[p] = ov; l4[p] = lv;
        }
        __builtin_nontemporal_store(o4, reinterpret_cast<f32x4*>(out_img + i0));
        __builtin_nontemporal_store(l4, reinterpret_cast<f32x4*>(lab_img + i0));
    } else {
        const int edge[4] = {0, 1, 2, NPIX - 1};
#pragma unroll
        for (int p = 0; p < 4; ++p) {
            float ov, lv;
            px_val(edge[p], pre0, gt0, pre1, gt1, pre2, gt2, pre3, gt3, mask, ov, lv);
            out_img[edge[p]] = ov;
            lab_img[edge[p]] = lv;
        }
    }
}

extern "C" void kernel_launch(void* const* d_in, const int* in_sizes, int n_in,
                              void* d_out, int out_size, void* d_ws, size_t ws_size,
                              hipStream_t stream) {
    // setup_inputs() dict order is INTERLEAVED: pre0, gt0, pre1, gt1, ...
    const float* pre0 = (const float*)d_in[0];
    const float* gt0  = (const float*)d_in[1];
    const float* pre1 = (const float*)d_in[2];
    const float* gt1  = (const float*)d_in[3];
    const float* pre2 = (const float*)d_in[4];
    const float* gt2  = (const float*)d_in[5];
    const float* pre3 = (const float*)d_in[6];
    const float* gt3  = (const float*)d_in[7];

    float* out = (float*)d_out;             // [0]=loss, [1..]=out_img, then lab_img
    float* pA  = (float*)d_ws;              // 5504 each, SoA planes
    float* pN  = pA + 5504;
    float* pQ  = pA + 11008;
    int*   mask = (int*)(pA + 16512);       // 128 ints

    k_err<<<5504, 256, 0, stream>>>(pre0, gt0, pre1, gt1, pre2, gt2, pre3, gt3, pA, pN, pQ);
    k_finalize<<<1, 256, 0, stream>>>(pA, pN, pQ, mask, out);
    k_write<<<16384, 256, 0, stream>>>(pre0, gt0, pre1, gt1, pre2, gt2, pre3, gt3, mask, out);
}